// Round 1
// baseline (5805.255 us; speedup 1.0000x reference)
//
#include <hip/hip_runtime.h>
#include <hip/hip_bf16.h>
#include <math.h>

#define H 128

// ---------------- encoder: h = x @ W + b ----------------
__global__ void k_encode(const float* __restrict__ x, const float* __restrict__ W,
                         const float* __restrict__ b, float* __restrict__ h,
                         int n, int in_dim)
{
    int idx = blockIdx.x * blockDim.x + threadIdx.x;
    if (idx >= n * H) return;
    int node = idx >> 7, hh = idx & (H - 1);
    float s = b[hh];
    const float* xr = x + (size_t)node * in_dim;
    for (int k = 0; k < in_dim; ++k) s += xr[k] * W[k * H + hh];
    h[idx] = s;
}

// ---------------- per-relation target counts ----------------
__global__ void k_count(const int* __restrict__ tgt, int E, float* __restrict__ cnt)
{
    int e = blockIdx.x * blockDim.x + threadIdx.x;
    if (e < E) unsafeAtomicAdd(&cnt[tgt[e]], 1.0f);
}

__global__ void k_recip(float* __restrict__ c, int n)
{
    int i = blockIdx.x * blockDim.x + threadIdx.x;
    if (i < n) { float v = c[i]; c[i] = (v > 1.0f) ? 1.0f / v : 1.0f; }
}

// ---------------- scatter-add of H-wide rows over edges ----------------
// thread i handles 4 floats of one edge: 32 threads/edge
__global__ void k_scatter(const float* __restrict__ hsrc, const int* __restrict__ src,
                          const int* __restrict__ tgt, int E, float* __restrict__ acc)
{
    long long i = (long long)blockIdx.x * blockDim.x + threadIdx.x;
    if (i >= (long long)E * 32) return;
    int e = (int)(i >> 5);
    int q = ((int)i & 31) << 2;
    int s = src[e], t = tgt[e];
    const float4 v = *(const float4*)(hsrc + (size_t)s * H + q);
    float* a = acc + (size_t)t * H + q;
    unsafeAtomicAdd(a + 0, v.x);
    unsafeAtomicAdd(a + 1, v.y);
    unsafeAtomicAdd(a + 2, v.z);
    unsafeAtomicAdd(a + 3, v.w);
}

// ---------------- out[i] += acc[i] * recip[i>>7] ----------------
__global__ void k_axpy_rows(const float* __restrict__ acc, const float* __restrict__ recip,
                            float* __restrict__ out, int total)
{
    int i = blockIdx.x * blockDim.x + threadIdx.x;
    if (i < total) out[i] += acc[i] * recip[i >> 7];
}

// ---------------- fused layer: elu(h@Wself + b + (acc*rsp + stat)@Wrel) ----------------
#define NPB 8
__global__ __launch_bounds__(H) void k_layer(
    const float* __restrict__ hin, const float* __restrict__ accsp,
    const float* __restrict__ rsp, const float* __restrict__ stat,
    const float* __restrict__ Wself, const float* __restrict__ bself,
    const float* __restrict__ Wrel, float* __restrict__ hout, int n)
{
    __shared__ float rows[NPB][H];
    __shared__ float aggs[NPB][H];
    int t = threadIdx.x;
    int base = blockIdx.x * NPB;
    for (int j = 0; j < NPB; ++j) {
        int nd = base + j; if (nd >= n) nd = n - 1;
        size_t o = (size_t)nd * H + t;
        rows[j][t] = hin[o];
        aggs[j][t] = accsp[o] * rsp[nd] + stat[o];
    }
    __syncthreads();

    float acc[NPB];
#pragma unroll
    for (int j = 0; j < NPB; ++j) acc[j] = 0.0f;

#pragma unroll 4
    for (int k = 0; k < H; ++k) {
        float ws = Wself[k * H + t];
        float wr = Wrel[k * H + t];
#pragma unroll
        for (int j = 0; j < NPB; ++j)
            acc[j] += rows[j][k] * ws + aggs[j][k] * wr;
    }

    float bb = bself[t];
    for (int j = 0; j < NPB; ++j) {
        int nd = base + j; if (nd >= n) break;
        float v = acc[j] + bb;
        hout[(size_t)nd * H + t] = (v > 0.0f) ? v : (expf(v) - 1.0f);
    }
}

extern "C" void kernel_launch(void* const* d_in, const int* in_sizes, int n_in,
                              void* d_out, int out_size, void* d_ws, size_t ws_size,
                              hipStream_t stream)
{
    // ---- inputs (setup_inputs order) ----
    const float* x_int  = (const float*)d_in[0];
    const float* x_lane = (const float*)d_in[1];
    const float* x_sens = (const float*)d_in[2];
    const float* x_inj  = (const float*)d_in[3];
    const int*   e_sp   = (const int*)d_in[4];
    const int*   e_fl   = (const int*)d_in[5];
    const int*   e_fs   = (const int*)d_in[6];
    const int*   e_in   = (const int*)d_in[7];
    const float* W_int  = (const float*)d_in[8];
    const float* b_int  = (const float*)d_in[9];
    const float* W_lane = (const float*)d_in[10];
    const float* b_lane = (const float*)d_in[11];
    const float* W_sens = (const float*)d_in[12];
    const float* b_sens = (const float*)d_in[13];
    const float* W_inj  = (const float*)d_in[14];
    const float* b_inj  = (const float*)d_in[15];
    const float* self_W = (const float*)d_in[16];
    const float* self_b = (const float*)d_in[17];
    const float* rel_W  = (const float*)d_in[18];

    const int n      = in_sizes[0] / 32;   // 50000 int nodes
    const int n_lane = in_sizes[1] / 16;
    const int n_sens = in_sizes[2] / 8;
    const int n_inj  = in_sizes[3] / 8;
    const int E_sp = in_sizes[4] / 2;
    const int E_fl = in_sizes[5] / 2;
    const int E_fs = in_sizes[6] / 2;
    const int E_in = in_sizes[7] / 2;

    float* out = (float*)d_out;

    // ---- workspace layout ----
    float* ws = (float*)d_ws;
    size_t o = 0;
    float* h_lane = ws + o; o += (size_t)n_lane * H;
    float* h_sens = ws + o; o += (size_t)n_sens * H;
    float* h_inj  = ws + o; o += (size_t)n_inj  * H;
    float* buf0   = ws + o; o += (size_t)n * H;
    float* buf1   = ws + o; o += (size_t)n * H;
    float* stat   = ws + o; o += (size_t)n * H;
    float* acc    = ws + o; o += (size_t)n * H;
    float* cnt    = ws + o; o += (size_t)4 * n;   // sp, lane, sens, inc
    float* r_sp   = cnt;
    float* r_la   = cnt + n;
    float* r_se   = cnt + 2 * (size_t)n;
    float* r_in   = cnt + 3 * (size_t)n;

    const int nh = n * H;

    // ---- counts -> reciprocals (input-only, once per call) ----
    hipMemsetAsync(cnt, 0, (size_t)4 * n * sizeof(float), stream);
    k_count<<<(E_sp + 255) / 256, 256, 0, stream>>>(e_sp + E_sp, E_sp, r_sp);
    k_count<<<(E_fl + 255) / 256, 256, 0, stream>>>(e_fl + E_fl, E_fl, r_la);
    k_count<<<(E_fs + 255) / 256, 256, 0, stream>>>(e_fs + E_fs, E_fs, r_se);
    k_count<<<(E_in + 255) / 256, 256, 0, stream>>>(e_in + E_in, E_in, r_in);
    k_recip<<<(4 * n + 255) / 256, 256, 0, stream>>>(cnt, 4 * n);

    // ---- encoders ----
    k_encode<<<((size_t)n * H + 255) / 256, 256, 0, stream>>>(x_int,  W_int,  b_int,  buf0,   n,      32);
    k_encode<<<((size_t)n_lane * H + 255) / 256, 256, 0, stream>>>(x_lane, W_lane, b_lane, h_lane, n_lane, 16);
    k_encode<<<((size_t)n_sens * H + 255) / 256, 256, 0, stream>>>(x_sens, W_sens, b_sens, h_sens, n_sens, 8);
    k_encode<<<((size_t)n_inj  * H + 255) / 256, 256, 0, stream>>>(x_inj,  W_inj,  b_inj,  h_inj,  n_inj,  8);

    // ---- layer-invariant aggregate: stat = mean_lane + mean_sens + mean_inj (pre-W) ----
    hipMemsetAsync(stat, 0, (size_t)nh * sizeof(float), stream);

    hipMemsetAsync(acc, 0, (size_t)nh * sizeof(float), stream);
    k_scatter<<<(int)(((long long)E_fl * 32 + 255) / 256), 256, 0, stream>>>(h_lane, e_fl, e_fl + E_fl, E_fl, acc);
    k_axpy_rows<<<(nh + 255) / 256, 256, 0, stream>>>(acc, r_la, stat, nh);

    hipMemsetAsync(acc, 0, (size_t)nh * sizeof(float), stream);
    k_scatter<<<(int)(((long long)E_fs * 32 + 255) / 256), 256, 0, stream>>>(h_sens, e_fs, e_fs + E_fs, E_fs, acc);
    k_axpy_rows<<<(nh + 255) / 256, 256, 0, stream>>>(acc, r_se, stat, nh);

    hipMemsetAsync(acc, 0, (size_t)nh * sizeof(float), stream);
    k_scatter<<<(int)(((long long)E_in * 32 + 255) / 256), 256, 0, stream>>>(h_inj, e_in, e_in + E_in, E_in, acc);
    k_axpy_rows<<<(nh + 255) / 256, 256, 0, stream>>>(acc, r_in, stat, nh);

    // ---- 3 layers ----
    const float* cur = buf0;
    for (int l = 0; l < 3; ++l) {
        hipMemsetAsync(acc, 0, (size_t)nh * sizeof(float), stream);
        k_scatter<<<(int)(((long long)E_sp * 32 + 255) / 256), 256, 0, stream>>>(cur, e_sp, e_sp + E_sp, E_sp, acc);
        float* nxt = (l == 2) ? out : ((cur == buf0) ? buf1 : buf0);
        k_layer<<<(n + NPB - 1) / NPB, H, 0, stream>>>(
            cur, acc, r_sp, stat,
            self_W + (size_t)l * H * H, self_b + (size_t)l * H,
            rel_W + (size_t)l * H * H, nxt, n);
        cur = nxt;
    }
}

// Round 2
// 1021.089 us; speedup vs baseline: 5.6854x; 5.6854x over previous
//
#include <hip/hip_runtime.h>
#include <hip/hip_bf16.h>
#include <math.h>

#define H 128
#define N_REL 4

// ---------------- encoder: h = x @ W + b ----------------
__global__ void k_encode(const float* __restrict__ x, const float* __restrict__ W,
                         const float* __restrict__ b, float* __restrict__ h,
                         int n, int in_dim)
{
    int idx = blockIdx.x * blockDim.x + threadIdx.x;
    if (idx >= n * H) return;
    int node = idx >> 7, hh = idx & (H - 1);
    float s = b[hh];
    const float* xr = x + (size_t)node * in_dim;
    for (int k = 0; k < in_dim; ++k) s += xr[k] * W[k * H + hh];
    h[idx] = s;
}

// ---------------- CSR build ----------------
__global__ void k_count(const int* __restrict__ tgt, int E, int* __restrict__ cnt)
{
    int e = blockIdx.x * blockDim.x + threadIdx.x;
    if (e < E) atomicAdd(&cnt[tgt[e]], 1);
}

// one block per relation: exclusive scan of counts -> rowptr, cursor copy, recip
__global__ __launch_bounds__(1024) void k_scan(const int* __restrict__ cnt_all,
                                               int* __restrict__ rowptr_all,
                                               int* __restrict__ cursor_all,
                                               float* __restrict__ recip_all, int n)
{
    int r = blockIdx.x;
    const int* cnt = cnt_all + (size_t)r * n;
    int* rowptr    = rowptr_all + (size_t)r * (n + 1);
    int* cursor    = cursor_all + (size_t)r * n;
    float* recip   = recip_all + (size_t)r * n;

    int tid = threadIdx.x;
    int per = (n + 1023) >> 10;
    int lo = tid * per;
    int hi = lo + per; if (hi > n) hi = n; if (lo > n) lo = n;

    int sum = 0;
    for (int i = lo; i < hi; ++i) sum += cnt[i];

    __shared__ int sh[1024];
    sh[tid] = sum;
    __syncthreads();
    for (int d = 1; d < 1024; d <<= 1) {
        int v = (tid >= d) ? sh[tid - d] : 0;
        __syncthreads();
        sh[tid] += v;
        __syncthreads();
    }
    int run = sh[tid] - sum;  // exclusive prefix
    for (int i = lo; i < hi; ++i) {
        int c = cnt[i];
        rowptr[i] = run;
        cursor[i] = run;
        recip[i] = 1.0f / (float)((c > 1) ? c : 1);
        run += c;
    }
    if (tid == 0) rowptr[n] = sh[1023];
}

__global__ void k_fill(const int* __restrict__ src, const int* __restrict__ tgt, int E,
                       int* __restrict__ cursor, int* __restrict__ col)
{
    int e = blockIdx.x * blockDim.x + threadIdx.x;
    if (e >= E) return;
    int t = tgt[e];
    int slot = atomicAdd(&cursor[t], 1);
    col[slot] = src[e];
}

// ---------------- SpMM: per-row gather + mean, fused epilogue ----------------
// MODE 0: out = acc*recip          (first static relation)
// MODE 1: out += acc*recip         (subsequent static relations)
// MODE 2: out = acc*recip + stat   (spatial relation -> agg)
template<int MODE>
__global__ __launch_bounds__(256) void k_spmm(const float* __restrict__ hsrc,
                                              const int* __restrict__ rowptr,
                                              const int* __restrict__ col,
                                              const float* __restrict__ recip,
                                              const float* __restrict__ stat,
                                              float* __restrict__ out, int n)
{
    int row = blockIdx.x * 8 + (threadIdx.x >> 5);
    if (row >= n) return;
    int lane = (threadIdx.x & 31) << 2;
    int beg = rowptr[row], end = rowptr[row + 1];

    float ax = 0.f, ay = 0.f, az = 0.f, aw = 0.f;
    int e = beg;
    for (; e + 4 <= end; e += 4) {
        int s0 = col[e], s1 = col[e + 1], s2 = col[e + 2], s3 = col[e + 3];
        const float4 v0 = *(const float4*)(hsrc + (size_t)s0 * H + lane);
        const float4 v1 = *(const float4*)(hsrc + (size_t)s1 * H + lane);
        const float4 v2 = *(const float4*)(hsrc + (size_t)s2 * H + lane);
        const float4 v3 = *(const float4*)(hsrc + (size_t)s3 * H + lane);
        ax += (v0.x + v1.x) + (v2.x + v3.x);
        ay += (v0.y + v1.y) + (v2.y + v3.y);
        az += (v0.z + v1.z) + (v2.z + v3.z);
        aw += (v0.w + v1.w) + (v2.w + v3.w);
    }
    for (; e < end; ++e) {
        int s0 = col[e];
        const float4 v0 = *(const float4*)(hsrc + (size_t)s0 * H + lane);
        ax += v0.x; ay += v0.y; az += v0.z; aw += v0.w;
    }

    float r = recip[row];
    size_t o = (size_t)row * H + lane;
    float4 res;
    if (MODE == 0) {
        res.x = ax * r; res.y = ay * r; res.z = az * r; res.w = aw * r;
    } else if (MODE == 1) {
        float4 p = *(const float4*)(out + o);
        res.x = p.x + ax * r; res.y = p.y + ay * r;
        res.z = p.z + az * r; res.w = p.w + aw * r;
    } else {
        float4 sv = *(const float4*)(stat + o);
        res.x = ax * r + sv.x; res.y = ay * r + sv.y;
        res.z = az * r + sv.z; res.w = aw * r + sv.w;
    }
    *(float4*)(out + o) = res;
}

// ---------------- fused layer: elu(h@Wself + b + agg@Wrel) ----------------
#define NPB 8
__global__ __launch_bounds__(H) void k_layer(
    const float* __restrict__ hin, const float* __restrict__ agg,
    const float* __restrict__ Wself, const float* __restrict__ bself,
    const float* __restrict__ Wrel, float* __restrict__ hout, int n)
{
    __shared__ float rows[NPB][H];
    __shared__ float aggs[NPB][H];
    int t = threadIdx.x;
    int base = blockIdx.x * NPB;
    for (int j = 0; j < NPB; ++j) {
        int nd = base + j; if (nd >= n) nd = n - 1;
        size_t o = (size_t)nd * H + t;
        rows[j][t] = hin[o];
        aggs[j][t] = agg[o];
    }
    __syncthreads();

    float acc[NPB];
#pragma unroll
    for (int j = 0; j < NPB; ++j) acc[j] = 0.0f;

#pragma unroll 4
    for (int k = 0; k < H; ++k) {
        float ws = Wself[k * H + t];
        float wr = Wrel[k * H + t];
#pragma unroll
        for (int j = 0; j < NPB; ++j)
            acc[j] += rows[j][k] * ws + aggs[j][k] * wr;
    }

    float bb = bself[t];
    for (int j = 0; j < NPB; ++j) {
        int nd = base + j; if (nd >= n) break;
        float v = acc[j] + bb;
        hout[(size_t)nd * H + t] = (v > 0.0f) ? v : (expf(v) - 1.0f);
    }
}

extern "C" void kernel_launch(void* const* d_in, const int* in_sizes, int n_in,
                              void* d_out, int out_size, void* d_ws, size_t ws_size,
                              hipStream_t stream)
{
    // ---- inputs (setup_inputs order) ----
    const float* x_int  = (const float*)d_in[0];
    const float* x_lane = (const float*)d_in[1];
    const float* x_sens = (const float*)d_in[2];
    const float* x_inj  = (const float*)d_in[3];
    const int*   e_sp   = (const int*)d_in[4];
    const int*   e_fl   = (const int*)d_in[5];
    const int*   e_fs   = (const int*)d_in[6];
    const int*   e_in   = (const int*)d_in[7];
    const float* W_int  = (const float*)d_in[8];
    const float* b_int  = (const float*)d_in[9];
    const float* W_lane = (const float*)d_in[10];
    const float* b_lane = (const float*)d_in[11];
    const float* W_sens = (const float*)d_in[12];
    const float* b_sens = (const float*)d_in[13];
    const float* W_inj  = (const float*)d_in[14];
    const float* b_inj  = (const float*)d_in[15];
    const float* self_W = (const float*)d_in[16];
    const float* self_b = (const float*)d_in[17];
    const float* rel_W  = (const float*)d_in[18];

    const int n      = in_sizes[0] / 32;   // 50000 int nodes (all relations target these)
    const int n_lane = in_sizes[1] / 16;
    const int n_sens = in_sizes[2] / 8;
    const int n_inj  = in_sizes[3] / 8;
    const int E[N_REL] = { in_sizes[4] / 2, in_sizes[5] / 2, in_sizes[6] / 2, in_sizes[7] / 2 };
    const int* esrc[N_REL] = { e_sp, e_fl, e_fs, e_in };

    float* out = (float*)d_out;

    // ---- workspace layout ----
    float* ws = (float*)d_ws;
    size_t o = 0;
    float* h_lane = ws + o; o += (size_t)n_lane * H;
    float* h_sens = ws + o; o += (size_t)n_sens * H;
    float* h_inj  = ws + o; o += (size_t)n_inj  * H;
    float* buf0   = ws + o; o += (size_t)n * H;
    float* stat   = ws + o; o += (size_t)n * H;
    float* agg    = ws + o; o += (size_t)n * H;
    float* recip  = ws + o; o += (size_t)N_REL * n;
    int* iws = (int*)(ws + o);
    size_t io = 0;
    int* cnt_all    = iws + io; io += (size_t)N_REL * n;
    int* rowptr_all = iws + io; io += (size_t)N_REL * (n + 1);
    int* cursor_all = iws + io; io += (size_t)N_REL * n;
    int* col_base   = iws + io;
    int* col[N_REL];
    {
        size_t c = 0;
        for (int r = 0; r < N_REL; ++r) { col[r] = col_base + c; c += E[r]; }
    }

    // ---- CSR build (edge lists are call-invariant inputs) ----
    hipMemsetAsync(cnt_all, 0, (size_t)N_REL * n * sizeof(int), stream);
    for (int r = 0; r < N_REL; ++r)
        k_count<<<(E[r] + 255) / 256, 256, 0, stream>>>(esrc[r] + E[r], E[r], cnt_all + (size_t)r * n);
    k_scan<<<N_REL, 1024, 0, stream>>>(cnt_all, rowptr_all, cursor_all, recip, n);
    for (int r = 0; r < N_REL; ++r)
        k_fill<<<(E[r] + 255) / 256, 256, 0, stream>>>(esrc[r], esrc[r] + E[r], E[r],
                                                       cursor_all + (size_t)r * n, col[r]);

    // ---- encoders ----
    k_encode<<<((size_t)n * H + 255) / 256, 256, 0, stream>>>(x_int,  W_int,  b_int,  buf0,   n,      32);
    k_encode<<<((size_t)n_lane * H + 255) / 256, 256, 0, stream>>>(x_lane, W_lane, b_lane, h_lane, n_lane, 16);
    k_encode<<<((size_t)n_sens * H + 255) / 256, 256, 0, stream>>>(x_sens, W_sens, b_sens, h_sens, n_sens, 8);
    k_encode<<<((size_t)n_inj  * H + 255) / 256, 256, 0, stream>>>(x_inj,  W_inj,  b_inj,  h_inj,  n_inj,  8);

    // ---- layer-invariant: stat = mean_lane + mean_sens + mean_inj ----
    const int spmm_grid = (n + 7) / 8;
    k_spmm<0><<<spmm_grid, 256, 0, stream>>>(h_lane, rowptr_all + 1 * (size_t)(n + 1), col[1],
                                             recip + 1 * (size_t)n, nullptr, stat, n);
    k_spmm<1><<<spmm_grid, 256, 0, stream>>>(h_sens, rowptr_all + 2 * (size_t)(n + 1), col[2],
                                             recip + 2 * (size_t)n, nullptr, stat, n);
    k_spmm<1><<<spmm_grid, 256, 0, stream>>>(h_inj,  rowptr_all + 3 * (size_t)(n + 1), col[3],
                                             recip + 3 * (size_t)n, nullptr, stat, n);

    // ---- 3 layers (ping-pong buf0 <-> out) ----
    const float* cur = buf0;
    for (int l = 0; l < 3; ++l) {
        k_spmm<2><<<spmm_grid, 256, 0, stream>>>(cur, rowptr_all, col[0],
                                                 recip, stat, agg, n);
        float* nxt = (l & 1) ? buf0 : out;
        k_layer<<<(n + NPB - 1) / NPB, H, 0, stream>>>(
            cur, agg,
            self_W + (size_t)l * H * H, self_b + (size_t)l * H,
            rel_W + (size_t)l * H * H, nxt, n);
        cur = nxt;
    }
}

// Round 3
// 623.744 us; speedup vs baseline: 9.3071x; 1.6370x over previous
//
#include <hip/hip_runtime.h>
#include <hip/hip_bf16.h>
#include <math.h>

#define H 128
#define N_REL 4
#define SB 64   // scan blocks per relation

typedef float f32x4 __attribute__((ext_vector_type(4)));
typedef __bf16 bf16x8 __attribute__((ext_vector_type(8)));

__device__ __forceinline__ unsigned short f2bf(float f) {
    return __builtin_bit_cast(unsigned short, (__bf16)f);
}
__device__ __forceinline__ void acc2(unsigned u, float& a, float& b) {
    union { unsigned u; float f; } x, y;
    x.u = u << 16; y.u = u & 0xffff0000u;
    a += x.f; b += y.f;
}

// ---------------- encoder: h = x @ W + b -> bf16 ----------------
__global__ void k_encode(const float* __restrict__ x, const float* __restrict__ W,
                         const float* __restrict__ b, unsigned short* __restrict__ h,
                         int n, int in_dim)
{
    int idx = blockIdx.x * blockDim.x + threadIdx.x;
    if (idx >= n * H) return;
    int node = idx >> 7, hh = idx & (H - 1);
    float s = b[hh];
    const float* xr = x + (size_t)node * in_dim;
    for (int k = 0; k < in_dim; ++k) s += xr[k] * W[k * H + hh];
    h[idx] = f2bf(s);
}

// ---------------- CSR build ----------------
__global__ void k_count(const int* __restrict__ tgt, int E, int* __restrict__ cnt)
{
    int e = blockIdx.x * blockDim.x + threadIdx.x;
    if (e < E) atomicAdd(&cnt[tgt[e]], 1);
}

// phase 1: per-chunk sums. grid = N_REL*SB
__global__ __launch_bounds__(256) void k_scan1(const int* __restrict__ cnt_all, int n,
                                               int* __restrict__ partial)
{
    int rel = blockIdx.x >> 6, blk = blockIdx.x & (SB - 1);
    int chunk = (n + SB - 1) / SB;
    int lo = blk * chunk, hi = min(lo + chunk, n);
    const int* cnt = cnt_all + (size_t)rel * n;
    int s = 0;
    for (int i = lo + threadIdx.x; i < hi; i += 256) s += cnt[i];
    __shared__ int sh[256];
    sh[threadIdx.x] = s; __syncthreads();
    for (int d = 128; d; d >>= 1) {
        if (threadIdx.x < d) sh[threadIdx.x] += sh[threadIdx.x + d];
        __syncthreads();
    }
    if (threadIdx.x == 0) partial[rel * SB + blk] = sh[0];
}

// phase 2: exclusive scan of 64 partials per relation (wave = relation)
__global__ __launch_bounds__(256) void k_scan2(int* __restrict__ partial,
                                               int* __restrict__ rowptr_all, int n, int4 Etot)
{
    int rel = threadIdx.x >> 6, lane = threadIdx.x & 63;
    int v = partial[rel * SB + lane];
    int inc = v;
    for (int d = 1; d < 64; d <<= 1) {
        int t = __shfl_up(inc, d);
        if (lane >= d) inc += t;
    }
    partial[rel * SB + lane] = inc - v;
    if (lane == 0) {
        int E = (rel == 0) ? Etot.x : (rel == 1) ? Etot.y : (rel == 2) ? Etot.z : Etot.w;
        rowptr_all[(size_t)rel * (n + 1) + n] = E;
    }
}

// phase 3: rescan chunk, write rowptr/cursor/recip
__global__ __launch_bounds__(256) void k_scan3(const int* __restrict__ cnt_all,
                                               const int* __restrict__ partial,
                                               int* __restrict__ rowptr_all,
                                               int* __restrict__ cursor_all,
                                               float* __restrict__ recip_all, int n)
{
    int rel = blockIdx.x >> 6, blk = blockIdx.x & (SB - 1);
    int chunk = (n + SB - 1) / SB;
    int lo = blk * chunk, hi = min(lo + chunk, n);
    const int* cnt = cnt_all + (size_t)rel * n;
    int per = (chunk + 255) >> 8;
    int tlo = min(lo + threadIdx.x * per, hi);
    int thi = min(tlo + per, hi);
    int s = 0;
    for (int i = tlo; i < thi; ++i) s += cnt[i];
    __shared__ int sh[256];
    sh[threadIdx.x] = s; __syncthreads();
    for (int d = 1; d < 256; d <<= 1) {
        int t = (threadIdx.x >= d) ? sh[threadIdx.x - d] : 0;
        __syncthreads();
        sh[threadIdx.x] += t;
        __syncthreads();
    }
    int run = partial[rel * SB + blk] + sh[threadIdx.x] - s;
    int* rowptr = rowptr_all + (size_t)rel * (n + 1);
    int* cursor = cursor_all + (size_t)rel * n;
    float* recip = recip_all + (size_t)rel * n;
    for (int i = tlo; i < thi; ++i) {
        int c = cnt[i];
        rowptr[i] = run;
        cursor[i] = run;
        recip[i] = 1.0f / (float)((c > 1) ? c : 1);
        run += c;
    }
}

__global__ void k_fill(const int* __restrict__ src, const int* __restrict__ tgt, int E,
                       int* __restrict__ cursor, int* __restrict__ col)
{
    int e = blockIdx.x * blockDim.x + threadIdx.x;
    if (e >= E) return;
    int slot = atomicAdd(&cursor[tgt[e]], 1);
    col[slot] = src[e];
}

// ---------------- SpMM: per-row bf16 gather + mean, fused epilogue ----------------
// MODE 0: stat  = acc*recip
// MODE 1: stat += acc*recip
// MODE 2: aggb  = bf16(acc*recip + stat)
template<int MODE>
__global__ __launch_bounds__(256) void k_spmm(const unsigned short* __restrict__ hsrc,
                                              const int* __restrict__ rowptr,
                                              const int* __restrict__ col,
                                              const float* __restrict__ recip,
                                              const float* __restrict__ stat,
                                              float* __restrict__ statout,
                                              unsigned short* __restrict__ aggout, int n)
{
    int row = blockIdx.x * 8 + (threadIdx.x >> 5);
    if (row >= n) return;
    int q = (threadIdx.x & 31) << 2;   // 4 bf16 per lane
    int beg = rowptr[row], end = rowptr[row + 1];

    float a0 = 0.f, a1 = 0.f, a2 = 0.f, a3 = 0.f;
    int e = beg;
    for (; e + 4 <= end; e += 4) {
        int s0 = col[e], s1 = col[e + 1], s2 = col[e + 2], s3 = col[e + 3];
        uint2 v0 = *(const uint2*)(hsrc + (size_t)s0 * H + q);
        uint2 v1 = *(const uint2*)(hsrc + (size_t)s1 * H + q);
        uint2 v2 = *(const uint2*)(hsrc + (size_t)s2 * H + q);
        uint2 v3 = *(const uint2*)(hsrc + (size_t)s3 * H + q);
        acc2(v0.x, a0, a1); acc2(v0.y, a2, a3);
        acc2(v1.x, a0, a1); acc2(v1.y, a2, a3);
        acc2(v2.x, a0, a1); acc2(v2.y, a2, a3);
        acc2(v3.x, a0, a1); acc2(v3.y, a2, a3);
    }
    for (; e < end; ++e) {
        uint2 v0 = *(const uint2*)(hsrc + (size_t)col[e] * H + q);
        acc2(v0.x, a0, a1); acc2(v0.y, a2, a3);
    }

    float r = recip[row];
    size_t o = (size_t)row * H + q;
    if (MODE == 0) {
        float4 res = { a0 * r, a1 * r, a2 * r, a3 * r };
        *(float4*)(statout + o) = res;
    } else if (MODE == 1) {
        float4 p = *(const float4*)(statout + o);
        p.x += a0 * r; p.y += a1 * r; p.z += a2 * r; p.w += a3 * r;
        *(float4*)(statout + o) = p;
    } else {
        float4 sv = *(const float4*)(stat + o);
        ushort4 w;
        w.x = f2bf(a0 * r + sv.x); w.y = f2bf(a1 * r + sv.y);
        w.z = f2bf(a2 * r + sv.z); w.w = f2bf(a3 * r + sv.w);
        *(ushort4*)(aggout + o) = w;
    }
}

// ---------------- MFMA layer: elu([h|agg] @ [Wself;Wrel] + b) ----------------
// block: 256 thr (4 waves), 64 rows; BT in LDS: [128 cols][256 k] bf16, XOR-swizzled
template<int LAST>
__global__ __launch_bounds__(256) void k_layer(const unsigned short* __restrict__ hb,
                                               const unsigned short* __restrict__ aggb,
                                               const float* __restrict__ Ws,
                                               const float* __restrict__ Wr,
                                               const float* __restrict__ bias,
                                               unsigned short* __restrict__ hbout,
                                               float* __restrict__ fout, int n)
{
    __shared__ __align__(16) char BT[128 * 256 * 2];

    int tid = threadIdx.x;
    // ---- fill BT[c][k] = W[k][c], bf16, swizzle: byte ^= (c&7)<<4 ----
    {
        int c = tid & 127, half = tid >> 7;
        for (int kc = half; kc < 32; kc += 2) {
            int kk0 = kc * 8;
            const float* Wsrc = (kk0 < 128) ? (Ws + (size_t)kk0 * H + c)
                                            : (Wr + (size_t)(kk0 - 128) * H + c);
            bf16x8 pack;
#pragma unroll
            for (int j = 0; j < 8; ++j) pack[j] = (__bf16)Wsrc[(size_t)j * H];
            int woff = c * 512 + ((kc * 16) ^ ((c & 7) << 4));
            *(bf16x8*)(BT + woff) = pack;
        }
    }

    int lane = tid & 63, wv = tid >> 6;
    int r16 = lane & 15, kgrp = lane >> 4;
    int rowbase = blockIdx.x * 64 + wv * 16;
    int arow = rowbase + r16; if (arow >= n) arow = n - 1;

    // ---- A fragments: 8 k-steps, 16B each ----
    bf16x8 afrag[8];
#pragma unroll
    for (int ks = 0; ks < 8; ++ks) {
        int k0 = ks * 32 + kgrp * 8;
        const unsigned short* src = (k0 < 128) ? (hb + (size_t)arow * H + k0)
                                               : (aggb + (size_t)arow * H + (k0 - 128));
        afrag[ks] = *(const bf16x8*)src;
    }
    __syncthreads();

    // ---- 8 col-tiles x 8 k-steps MFMA ----
#pragma unroll
    for (int ct = 0; ct < 8; ++ct) {
        int c = ct * 16 + r16;
        f32x4 acc = { 0.f, 0.f, 0.f, 0.f };
#pragma unroll
        for (int ks = 0; ks < 8; ++ks) {
            int kbyte = ks * 64 + kgrp * 16;
            int off = c * 512 + (kbyte ^ ((c & 7) << 4));
            bf16x8 bfrag = *(const bf16x8*)(BT + off);
            acc = __builtin_amdgcn_mfma_f32_16x16x32_bf16(afrag[ks], bfrag, acc, 0, 0, 0);
        }
        float bb = bias[c];
#pragma unroll
        for (int i = 0; i < 4; ++i) {
            int grow = rowbase + kgrp * 4 + i;
            if (grow < n) {
                float v = acc[i] + bb;
                v = (v > 0.f) ? v : (expf(v) - 1.f);
                if (LAST) fout[(size_t)grow * H + c] = v;
                else      hbout[(size_t)grow * H + c] = f2bf(v);
            }
        }
    }
}

extern "C" void kernel_launch(void* const* d_in, const int* in_sizes, int n_in,
                              void* d_out, int out_size, void* d_ws, size_t ws_size,
                              hipStream_t stream)
{
    const float* x_int  = (const float*)d_in[0];
    const float* x_lane = (const float*)d_in[1];
    const float* x_sens = (const float*)d_in[2];
    const float* x_inj  = (const float*)d_in[3];
    const int*   e_sp   = (const int*)d_in[4];
    const int*   e_fl   = (const int*)d_in[5];
    const int*   e_fs   = (const int*)d_in[6];
    const int*   e_in   = (const int*)d_in[7];
    const float* W_int  = (const float*)d_in[8];
    const float* b_int  = (const float*)d_in[9];
    const float* W_lane = (const float*)d_in[10];
    const float* b_lane = (const float*)d_in[11];
    const float* W_sens = (const float*)d_in[12];
    const float* b_sens = (const float*)d_in[13];
    const float* W_inj  = (const float*)d_in[14];
    const float* b_inj  = (const float*)d_in[15];
    const float* self_W = (const float*)d_in[16];
    const float* self_b = (const float*)d_in[17];
    const float* rel_W  = (const float*)d_in[18];

    const int n      = in_sizes[0] / 32;
    const int n_lane = in_sizes[1] / 16;
    const int n_sens = in_sizes[2] / 8;
    const int n_inj  = in_sizes[3] / 8;
    const int E[N_REL] = { in_sizes[4] / 2, in_sizes[5] / 2, in_sizes[6] / 2, in_sizes[7] / 2 };
    const int* esrc[N_REL] = { e_sp, e_fl, e_fs, e_in };

    float* out = (float*)d_out;

    // ---- workspace carve (16B-aligned chunks) ----
    char* base = (char*)d_ws;
    size_t off = 0;
    auto carve = [&](size_t bytes) { char* p = base + off; off += (bytes + 15) & ~(size_t)15; return p; };
    unsigned short* hb_lane = (unsigned short*)carve((size_t)n_lane * H * 2);
    unsigned short* hb_sens = (unsigned short*)carve((size_t)n_sens * H * 2);
    unsigned short* hb_inj  = (unsigned short*)carve((size_t)n_inj  * H * 2);
    unsigned short* hb_a    = (unsigned short*)carve((size_t)n * H * 2);
    unsigned short* hb_b    = (unsigned short*)carve((size_t)n * H * 2);
    unsigned short* aggb    = (unsigned short*)carve((size_t)n * H * 2);
    float* stat   = (float*)carve((size_t)n * H * 4);
    float* recip  = (float*)carve((size_t)N_REL * n * 4);
    int* cnt_all    = (int*)carve((size_t)N_REL * n * 4);
    int* rowptr_all = (int*)carve((size_t)N_REL * (n + 1) * 4);
    int* cursor_all = (int*)carve((size_t)N_REL * n * 4);
    int* partial    = (int*)carve((size_t)N_REL * SB * 4);
    int* col[N_REL];
    for (int r = 0; r < N_REL; ++r) col[r] = (int*)carve((size_t)E[r] * 4);

    // ---- CSR build ----
    hipMemsetAsync(cnt_all, 0, (size_t)N_REL * n * sizeof(int), stream);
    for (int r = 0; r < N_REL; ++r)
        k_count<<<(E[r] + 255) / 256, 256, 0, stream>>>(esrc[r] + E[r], E[r], cnt_all + (size_t)r * n);
    k_scan1<<<N_REL * SB, 256, 0, stream>>>(cnt_all, n, partial);
    int4 Etot = { E[0], E[1], E[2], E[3] };
    k_scan2<<<1, 256, 0, stream>>>(partial, rowptr_all, n, Etot);
    k_scan3<<<N_REL * SB, 256, 0, stream>>>(cnt_all, partial, rowptr_all, cursor_all, recip, n);
    for (int r = 0; r < N_REL; ++r)
        k_fill<<<(E[r] + 255) / 256, 256, 0, stream>>>(esrc[r], esrc[r] + E[r], E[r],
                                                       cursor_all + (size_t)r * n, col[r]);

    // ---- encoders (bf16 out) ----
    k_encode<<<((size_t)n * H + 255) / 256, 256, 0, stream>>>(x_int,  W_int,  b_int,  hb_a,    n,      32);
    k_encode<<<((size_t)n_lane * H + 255) / 256, 256, 0, stream>>>(x_lane, W_lane, b_lane, hb_lane, n_lane, 16);
    k_encode<<<((size_t)n_sens * H + 255) / 256, 256, 0, stream>>>(x_sens, W_sens, b_sens, hb_sens, n_sens, 8);
    k_encode<<<((size_t)n_inj  * H + 255) / 256, 256, 0, stream>>>(x_inj,  W_inj,  b_inj,  hb_inj,  n_inj,  8);

    // ---- layer-invariant static aggregate ----
    const int spmm_grid = (n + 7) / 8;
    k_spmm<0><<<spmm_grid, 256, 0, stream>>>(hb_lane, rowptr_all + 1 * (size_t)(n + 1), col[1],
                                             recip + 1 * (size_t)n, nullptr, stat, nullptr, n);
    k_spmm<1><<<spmm_grid, 256, 0, stream>>>(hb_sens, rowptr_all + 2 * (size_t)(n + 1), col[2],
                                             recip + 2 * (size_t)n, nullptr, stat, nullptr, n);
    k_spmm<1><<<spmm_grid, 256, 0, stream>>>(hb_inj,  rowptr_all + 3 * (size_t)(n + 1), col[3],
                                             recip + 3 * (size_t)n, nullptr, stat, nullptr, n);

    // ---- 3 layers ----
    const int layer_grid = (n + 63) / 64;
    unsigned short* cur = hb_a;
    unsigned short* nxt = hb_b;
    for (int l = 0; l < 3; ++l) {
        k_spmm<2><<<spmm_grid, 256, 0, stream>>>(cur, rowptr_all, col[0],
                                                 recip, stat, nullptr, aggb, n);
        const float* Ws = self_W + (size_t)l * H * H;
        const float* Wr = rel_W  + (size_t)l * H * H;
        const float* bb = self_b + (size_t)l * H;
        if (l == 2)
            k_layer<1><<<layer_grid, 256, 0, stream>>>(cur, aggb, Ws, Wr, bb, nullptr, out, n);
        else
            k_layer<0><<<layer_grid, 256, 0, stream>>>(cur, aggb, Ws, Wr, bb, nxt, nullptr, n);
        unsigned short* t = cur; cur = nxt; nxt = t;
    }
}

// Round 4
// 433.621 us; speedup vs baseline: 13.3879x; 1.4385x over previous
//
#include <hip/hip_runtime.h>
#include <hip/hip_bf16.h>
#include <math.h>

#define H 128
#define N_REL 4
#define SB 64   // scan blocks per relation

typedef float f32x4 __attribute__((ext_vector_type(4)));
typedef __bf16 bf16x8 __attribute__((ext_vector_type(8)));

__device__ __forceinline__ unsigned short f2bf(float f) {
    return __builtin_bit_cast(unsigned short, (__bf16)f);
}
__device__ __forceinline__ void acc2(unsigned u, float& a, float& b) {
    union { unsigned u; float f; } x, y;
    x.u = u << 16; y.u = u & 0xffff0000u;
    a += x.f; b += y.f;
}

// ---------------- CSR build ----------------
__global__ void k_count(const int* __restrict__ tgt, int E, int* __restrict__ cnt)
{
    int e = blockIdx.x * blockDim.x + threadIdx.x;
    if (e < E) atomicAdd(&cnt[tgt[e]], 1);
}

__global__ __launch_bounds__(256) void k_scan1(const int* __restrict__ cnt_all, int n,
                                               int* __restrict__ partial)
{
    int rel = blockIdx.x >> 6, blk = blockIdx.x & (SB - 1);
    int chunk = (n + SB - 1) / SB;
    int lo = blk * chunk, hi = min(lo + chunk, n);
    const int* cnt = cnt_all + (size_t)rel * n;
    int s = 0;
    for (int i = lo + threadIdx.x; i < hi; i += 256) s += cnt[i];
    __shared__ int sh[256];
    sh[threadIdx.x] = s; __syncthreads();
    for (int d = 128; d; d >>= 1) {
        if (threadIdx.x < d) sh[threadIdx.x] += sh[threadIdx.x + d];
        __syncthreads();
    }
    if (threadIdx.x == 0) partial[rel * SB + blk] = sh[0];
}

__global__ __launch_bounds__(256) void k_scan2(int* __restrict__ partial,
                                               int* __restrict__ rowptr_all, int n, int4 Etot)
{
    int rel = threadIdx.x >> 6, lane = threadIdx.x & 63;
    int v = partial[rel * SB + lane];
    int inc = v;
    for (int d = 1; d < 64; d <<= 1) {
        int t = __shfl_up(inc, d);
        if (lane >= d) inc += t;
    }
    partial[rel * SB + lane] = inc - v;
    if (lane == 0) {
        int E = (rel == 0) ? Etot.x : (rel == 1) ? Etot.y : (rel == 2) ? Etot.z : Etot.w;
        rowptr_all[(size_t)rel * (n + 1) + n] = E;
    }
}

// recip = (c>0) ? 1/c : 0   (0 also serves as the "has edges" mask for bias)
__global__ __launch_bounds__(256) void k_scan3(const int* __restrict__ cnt_all,
                                               const int* __restrict__ partial,
                                               int* __restrict__ rowptr_all,
                                               int* __restrict__ cursor_all,
                                               float* __restrict__ recip_all, int n)
{
    int rel = blockIdx.x >> 6, blk = blockIdx.x & (SB - 1);
    int chunk = (n + SB - 1) / SB;
    int lo = blk * chunk, hi = min(lo + chunk, n);
    const int* cnt = cnt_all + (size_t)rel * n;
    int per = (chunk + 255) >> 8;
    int tlo = min(lo + threadIdx.x * per, hi);
    int thi = min(tlo + per, hi);
    int s = 0;
    for (int i = tlo; i < thi; ++i) s += cnt[i];
    __shared__ int sh[256];
    sh[threadIdx.x] = s; __syncthreads();
    for (int d = 1; d < 256; d <<= 1) {
        int t = (threadIdx.x >= d) ? sh[threadIdx.x - d] : 0;
        __syncthreads();
        sh[threadIdx.x] += t;
        __syncthreads();
    }
    int run = partial[rel * SB + blk] + sh[threadIdx.x] - s;
    int* rowptr = rowptr_all + (size_t)rel * (n + 1);
    int* cursor = cursor_all + (size_t)rel * n;
    float* recip = recip_all + (size_t)rel * n;
    for (int i = tlo; i < thi; ++i) {
        int c = cnt[i];
        rowptr[i] = run;
        cursor[i] = run;
        recip[i] = (c > 0) ? 1.0f / (float)c : 0.0f;
        run += c;
    }
}

__global__ void k_fill(const int* __restrict__ src, const int* __restrict__ tgt, int E,
                       int* __restrict__ cursor, int* __restrict__ col)
{
    int e = blockIdx.x * blockDim.x + threadIdx.x;
    if (e >= E) return;
    int slot = atomicAdd(&cursor[tgt[e]], 1);
    col[slot] = src[e];
}

// ---------------- MFMA encoder for x_int (K=32, one MFMA step) ----------------
// block 256 = 4 waves x 16 rows; W staged in LDS [col][k] bf16, col stride 80B
__global__ __launch_bounds__(256) void k_encmfma(const float* __restrict__ x,
                                                 const float* __restrict__ W,
                                                 const float* __restrict__ b,
                                                 unsigned short* __restrict__ h, int n)
{
    __shared__ __align__(16) char WB[128 * 80];
    int tid = threadIdx.x;
    {
        int c = tid & 127, khalf = tid >> 7;
        for (int kk = 0; kk < 16; ++kk) {
            int k = khalf * 16 + kk;
            *(unsigned short*)(WB + c * 80 + k * 2) = f2bf(W[(size_t)k * H + c]);
        }
    }
    int lane = tid & 63, wv = tid >> 6;
    int r16 = lane & 15, kgrp = lane >> 4;
    int rowbase = blockIdx.x * 64 + wv * 16;
    int arow = rowbase + r16; if (arow >= n) arow = n - 1;
    const float* xr = x + (size_t)arow * 32 + kgrp * 8;
    float4 xa = *(const float4*)xr, xb = *(const float4*)(xr + 4);
    bf16x8 af;
    af[0] = (__bf16)xa.x; af[1] = (__bf16)xa.y; af[2] = (__bf16)xa.z; af[3] = (__bf16)xa.w;
    af[4] = (__bf16)xb.x; af[5] = (__bf16)xb.y; af[6] = (__bf16)xb.z; af[7] = (__bf16)xb.w;
    __syncthreads();
#pragma unroll
    for (int ct = 0; ct < 8; ++ct) {
        int c = ct * 16 + r16;
        bf16x8 bf = *(const bf16x8*)(WB + c * 80 + kgrp * 16);
        f32x4 acc = { 0.f, 0.f, 0.f, 0.f };
        acc = __builtin_amdgcn_mfma_f32_16x16x32_bf16(af, bf, acc, 0, 0, 0);
        float bb = b[c];
#pragma unroll
        for (int i = 0; i < 4; ++i) {
            int grow = rowbase + kgrp * 4 + i;
            if (grow < n) h[(size_t)grow * H + c] = f2bf(acc[i] + bb);
        }
    }
}

// ---------------- static relations: gather-mean of RAW x (D dims) ----------------
template<int D>
__global__ __launch_bounds__(256) void k_aggx(const float* __restrict__ x,
                                              const int* __restrict__ rowptr,
                                              const int* __restrict__ col,
                                              const float* __restrict__ recip,
                                              float* __restrict__ out, int n)
{
    const int rpb = 256 / D;
    int row = blockIdx.x * rpb + threadIdx.x / D;
    if (row >= n) return;
    int d = threadIdx.x & (D - 1);
    int beg = rowptr[row], end = rowptr[row + 1];
    float s0 = 0.f, s1 = 0.f;
    int e = beg;
    for (; e + 2 <= end; e += 2) {
        s0 += x[(size_t)col[e] * D + d];
        s1 += x[(size_t)col[e + 1] * D + d];
    }
    if (e < end) s0 += x[(size_t)col[e] * D + d];
    out[(size_t)row * D + d] = (s0 + s1) * recip[row];
}

// ---------------- stat = XL@WL + bL*[cL>0] + XS@WS + bS*[..] + XI@WI + bI*[..] ----------------
__global__ __launch_bounds__(256) void k_stat(
    const float* __restrict__ XL, const float* __restrict__ XS, const float* __restrict__ XI,
    const float* __restrict__ WL, const float* __restrict__ WSn, const float* __restrict__ WI,
    const float* __restrict__ bL, const float* __restrict__ bS, const float* __restrict__ bI,
    const float* __restrict__ rL, const float* __restrict__ rS, const float* __restrict__ rI,
    float* __restrict__ stat, int n)
{
    __shared__ float Wc[32][128];
    __shared__ float xs[8][32];
    int t = threadIdx.x;
    for (int i = t; i < 16 * 128; i += 256) Wc[i >> 7][i & 127] = WL[i];
    for (int i = t; i < 8 * 128; i += 256)  Wc[16 + (i >> 7)][i & 127] = WSn[i];
    for (int i = t; i < 8 * 128; i += 256)  Wc[24 + (i >> 7)][i & 127] = WI[i];
    {
        int rr = t >> 5, k = t & 31;
        int rrow = blockIdx.x * 8 + rr; if (rrow >= n) rrow = n - 1;
        float v;
        if (k < 16)      v = XL[(size_t)rrow * 16 + k];
        else if (k < 24) v = XS[(size_t)rrow * 8 + (k - 16)];
        else             v = XI[(size_t)rrow * 8 + (k - 24)];
        xs[rr][k] = v;
    }
    __syncthreads();
    int rl = t >> 5, c4 = (t & 31) << 2;
    int row = blockIdx.x * 8 + rl;
    float a0 = 0.f, a1 = 0.f, a2 = 0.f, a3 = 0.f;
#pragma unroll
    for (int k = 0; k < 32; ++k) {
        float xv = xs[rl][k];
        a0 += xv * Wc[k][c4 + 0]; a1 += xv * Wc[k][c4 + 1];
        a2 += xv * Wc[k][c4 + 2]; a3 += xv * Wc[k][c4 + 3];
    }
    if (row < n) {
        float mL = (rL[row] > 0.f) ? 1.f : 0.f;
        float mS = (rS[row] > 0.f) ? 1.f : 0.f;
        float mI = (rI[row] > 0.f) ? 1.f : 0.f;
        float4 res;
        res.x = a0 + mL * bL[c4 + 0] + mS * bS[c4 + 0] + mI * bI[c4 + 0];
        res.y = a1 + mL * bL[c4 + 1] + mS * bS[c4 + 1] + mI * bI[c4 + 1];
        res.z = a2 + mL * bL[c4 + 2] + mS * bS[c4 + 2] + mI * bI[c4 + 2];
        res.w = a3 + mL * bL[c4 + 3] + mS * bS[c4 + 3] + mI * bI[c4 + 3];
        *(float4*)(stat + (size_t)row * H + c4) = res;
    }
}

// ---------------- spatial SpMM: aggb = bf16(mean(hb_nbr) + stat) ----------------
__global__ __launch_bounds__(256) void k_spmm(const unsigned short* __restrict__ hsrc,
                                              const int* __restrict__ rowptr,
                                              const int* __restrict__ col,
                                              const float* __restrict__ recip,
                                              const float* __restrict__ stat,
                                              unsigned short* __restrict__ aggout, int n)
{
    int row = blockIdx.x * 8 + (threadIdx.x >> 5);
    if (row >= n) return;
    int q = (threadIdx.x & 31) << 2;
    int beg = rowptr[row], end = rowptr[row + 1];

    float a0 = 0.f, a1 = 0.f, a2 = 0.f, a3 = 0.f;
    int e = beg;
    for (; e + 4 <= end; e += 4) {
        int s0 = col[e], s1 = col[e + 1], s2 = col[e + 2], s3 = col[e + 3];
        uint2 v0 = *(const uint2*)(hsrc + (size_t)s0 * H + q);
        uint2 v1 = *(const uint2*)(hsrc + (size_t)s1 * H + q);
        uint2 v2 = *(const uint2*)(hsrc + (size_t)s2 * H + q);
        uint2 v3 = *(const uint2*)(hsrc + (size_t)s3 * H + q);
        acc2(v0.x, a0, a1); acc2(v0.y, a2, a3);
        acc2(v1.x, a0, a1); acc2(v1.y, a2, a3);
        acc2(v2.x, a0, a1); acc2(v2.y, a2, a3);
        acc2(v3.x, a0, a1); acc2(v3.y, a2, a3);
    }
    for (; e < end; ++e) {
        uint2 v0 = *(const uint2*)(hsrc + (size_t)col[e] * H + q);
        acc2(v0.x, a0, a1); acc2(v0.y, a2, a3);
    }

    float r = recip[row];
    size_t o = (size_t)row * H + q;
    float4 sv = *(const float4*)(stat + o);
    ushort4 w;
    w.x = f2bf(a0 * r + sv.x); w.y = f2bf(a1 * r + sv.y);
    w.z = f2bf(a2 * r + sv.z); w.w = f2bf(a3 * r + sv.w);
    *(ushort4*)(aggout + o) = w;
}

// ---------------- MFMA layer: elu([h|agg] @ [Wself;Wrel] + b) ----------------
template<int LAST>
__global__ __launch_bounds__(256) void k_layer(const unsigned short* __restrict__ hb,
                                               const unsigned short* __restrict__ aggb,
                                               const float* __restrict__ Ws,
                                               const float* __restrict__ Wr,
                                               const float* __restrict__ bias,
                                               unsigned short* __restrict__ hbout,
                                               float* __restrict__ fout, int n)
{
    __shared__ __align__(16) char BT[128 * 256 * 2];

    int tid = threadIdx.x;
    {
        int c = tid & 127, half = tid >> 7;
        for (int kc = half; kc < 32; kc += 2) {
            int kk0 = kc * 8;
            const float* Wsrc = (kk0 < 128) ? (Ws + (size_t)kk0 * H + c)
                                            : (Wr + (size_t)(kk0 - 128) * H + c);
            bf16x8 pack;
#pragma unroll
            for (int j = 0; j < 8; ++j) pack[j] = (__bf16)Wsrc[(size_t)j * H];
            int woff = c * 512 + ((kc * 16) ^ ((c & 7) << 4));
            *(bf16x8*)(BT + woff) = pack;
        }
    }

    int lane = tid & 63, wv = tid >> 6;
    int r16 = lane & 15, kgrp = lane >> 4;
    int rowbase = blockIdx.x * 64 + wv * 16;
    int arow = rowbase + r16; if (arow >= n) arow = n - 1;

    bf16x8 afrag[8];
#pragma unroll
    for (int ks = 0; ks < 8; ++ks) {
        int k0 = ks * 32 + kgrp * 8;
        const unsigned short* src = (k0 < 128) ? (hb + (size_t)arow * H + k0)
                                               : (aggb + (size_t)arow * H + (k0 - 128));
        afrag[ks] = *(const bf16x8*)src;
    }
    __syncthreads();

#pragma unroll
    for (int ct = 0; ct < 8; ++ct) {
        int c = ct * 16 + r16;
        f32x4 acc = { 0.f, 0.f, 0.f, 0.f };
#pragma unroll
        for (int ks = 0; ks < 8; ++ks) {
            int kbyte = ks * 64 + kgrp * 16;
            int off = c * 512 + (kbyte ^ ((c & 7) << 4));
            bf16x8 bfrag = *(const bf16x8*)(BT + off);
            acc = __builtin_amdgcn_mfma_f32_16x16x32_bf16(afrag[ks], bfrag, acc, 0, 0, 0);
        }
        float bb = bias[c];
#pragma unroll
        for (int i = 0; i < 4; ++i) {
            int grow = rowbase + kgrp * 4 + i;
            if (grow < n) {
                float v = acc[i] + bb;
                v = (v > 0.f) ? v : (expf(v) - 1.f);
                if (LAST) fout[(size_t)grow * H + c] = v;
                else      hbout[(size_t)grow * H + c] = f2bf(v);
            }
        }
    }
}

extern "C" void kernel_launch(void* const* d_in, const int* in_sizes, int n_in,
                              void* d_out, int out_size, void* d_ws, size_t ws_size,
                              hipStream_t stream)
{
    const float* x_int  = (const float*)d_in[0];
    const float* x_lane = (const float*)d_in[1];
    const float* x_sens = (const float*)d_in[2];
    const float* x_inj  = (const float*)d_in[3];
    const int*   e_sp   = (const int*)d_in[4];
    const int*   e_fl   = (const int*)d_in[5];
    const int*   e_fs   = (const int*)d_in[6];
    const int*   e_in   = (const int*)d_in[7];
    const float* W_int  = (const float*)d_in[8];
    const float* b_int  = (const float*)d_in[9];
    const float* W_lane = (const float*)d_in[10];
    const float* b_lane = (const float*)d_in[11];
    const float* W_sens = (const float*)d_in[12];
    const float* b_sens = (const float*)d_in[13];
    const float* W_inj  = (const float*)d_in[14];
    const float* b_inj  = (const float*)d_in[15];
    const float* self_W = (const float*)d_in[16];
    const float* self_b = (const float*)d_in[17];
    const float* rel_W  = (const float*)d_in[18];

    const int n = in_sizes[0] / 32;
    const int E[N_REL] = { in_sizes[4] / 2, in_sizes[5] / 2, in_sizes[6] / 2, in_sizes[7] / 2 };
    const int* esrc[N_REL] = { e_sp, e_fl, e_fs, e_in };

    float* out = (float*)d_out;

    // ---- workspace carve ----
    char* base = (char*)d_ws;
    size_t off = 0;
    auto carve = [&](size_t bytes) { char* p = base + off; off += (bytes + 15) & ~(size_t)15; return p; };
    unsigned short* hb_a = (unsigned short*)carve((size_t)n * H * 2);
    unsigned short* hb_b = (unsigned short*)carve((size_t)n * H * 2);
    unsigned short* aggb = (unsigned short*)carve((size_t)n * H * 2);
    float* stat  = (float*)carve((size_t)n * H * 4);
    float* XL    = (float*)carve((size_t)n * 16 * 4);
    float* XS    = (float*)carve((size_t)n * 8 * 4);
    float* XI    = (float*)carve((size_t)n * 8 * 4);
    float* recip = (float*)carve((size_t)N_REL * n * 4);
    int* cnt_all    = (int*)carve((size_t)N_REL * n * 4);
    int* rowptr_all = (int*)carve((size_t)N_REL * (n + 1) * 4);
    int* cursor_all = (int*)carve((size_t)N_REL * n * 4);
    int* partial    = (int*)carve((size_t)N_REL * SB * 4);
    int* col[N_REL];
    for (int r = 0; r < N_REL; ++r) col[r] = (int*)carve((size_t)E[r] * 4);

    // ---- CSR build ----
    hipMemsetAsync(cnt_all, 0, (size_t)N_REL * n * sizeof(int), stream);
    for (int r = 0; r < N_REL; ++r)
        k_count<<<(E[r] + 255) / 256, 256, 0, stream>>>(esrc[r] + E[r], E[r], cnt_all + (size_t)r * n);
    k_scan1<<<N_REL * SB, 256, 0, stream>>>(cnt_all, n, partial);
    int4 Etot = { E[0], E[1], E[2], E[3] };
    k_scan2<<<1, 256, 0, stream>>>(partial, rowptr_all, n, Etot);
    k_scan3<<<N_REL * SB, 256, 0, stream>>>(cnt_all, partial, rowptr_all, cursor_all, recip, n);
    for (int r = 0; r < N_REL; ++r)
        k_fill<<<(E[r] + 255) / 256, 256, 0, stream>>>(esrc[r], esrc[r] + E[r], E[r],
                                                       cursor_all + (size_t)r * n, col[r]);

    const int* rp1 = rowptr_all + 1 * (size_t)(n + 1);
    const int* rp2 = rowptr_all + 2 * (size_t)(n + 1);
    const int* rp3 = rowptr_all + 3 * (size_t)(n + 1);
    const float* r0 = recip;
    const float* r1 = recip + (size_t)n;
    const float* r2 = recip + 2 * (size_t)n;
    const float* r3 = recip + 3 * (size_t)n;

    // ---- x_int encoder (MFMA) ----
    k_encmfma<<<(n + 63) / 64, 256, 0, stream>>>(x_int, W_int, b_int, hb_a, n);

    // ---- static relations on RAW x, then small fused GEMM -> stat ----
    k_aggx<16><<<(n + 15) / 16, 256, 0, stream>>>(x_lane, rp1, col[1], r1, XL, n);
    k_aggx<8><<<(n + 31) / 32, 256, 0, stream>>>(x_sens, rp2, col[2], r2, XS, n);
    k_aggx<8><<<(n + 31) / 32, 256, 0, stream>>>(x_inj,  rp3, col[3], r3, XI, n);
    k_stat<<<(n + 7) / 8, 256, 0, stream>>>(XL, XS, XI, W_lane, W_sens, W_inj,
                                            b_lane, b_sens, b_inj, r1, r2, r3, stat, n);

    // ---- 3 layers ----
    const int spmm_grid = (n + 7) / 8;
    const int layer_grid = (n + 63) / 64;
    unsigned short* cur = hb_a;
    unsigned short* nxt = hb_b;
    for (int l = 0; l < 3; ++l) {
        k_spmm<<<spmm_grid, 256, 0, stream>>>(cur, rowptr_all, col[0], r0, stat, aggb, n);
        const float* Ws = self_W + (size_t)l * H * H;
        const float* Wr = rel_W  + (size_t)l * H * H;
        const float* bb = self_b + (size_t)l * H;
        if (l == 2)
            k_layer<1><<<layer_grid, 256, 0, stream>>>(cur, aggb, Ws, Wr, bb, nullptr, out, n);
        else
            k_layer<0><<<layer_grid, 256, 0, stream>>>(cur, aggb, Ws, Wr, bb, nxt, nullptr, n);
        unsigned short* t = cur; cur = nxt; nxt = t;
    }
}